// Round 10
// baseline (450.832 us; speedup 1.0000x reference)
//
#include <hip/hip_runtime.h>
#include <math.h>

#define HEADS 4
#define CH 256
#define HC 1024
#define NSLICE 8
#define NEG_SLOPE 0.2f
#define EPSQ 1e-16f
#define AGG_T 32  // CSR slots per 16-lane group (128 starved occupancy, R9)

typedef __attribute__((ext_vector_type(8))) short bf16x8;
typedef __attribute__((ext_vector_type(4))) float f32x4;

static inline int cdiv(int a, int b) { return (a + b - 1) / b; }

__device__ __forceinline__ unsigned short f2bf(float f) {
  unsigned u = __float_as_uint(f);
  u += 0x7FFFu + ((u >> 16) & 1u);  // RNE
  return (unsigned short)(u >> 16);
}
__device__ __forceinline__ float bf2f(unsigned short s) {
  return __uint_as_float(((unsigned)s) << 16);
}
__device__ __forceinline__ void gload_lds16(const void* g, void* l) {
  __builtin_amdgcn_global_load_lds((const __attribute__((address_space(1))) void*)g,
                                   (__attribute__((address_space(3))) void*)l, 16, 0, 0);
}

// ---------------- CSR build ----------------
__global__ void k_count(const int* __restrict__ ei, int E, int ET, int* __restrict__ cnt) {
  int e = blockIdx.x * blockDim.x + threadIdx.x;
  if (e >= ET) return;
  int d = (e < E) ? ei[E + e] : (e - E);
  atomicAdd(&cnt[d], 1);
}

__global__ __launch_bounds__(1024) void k_scan(const int* __restrict__ counts,
                                               int* __restrict__ offsets, int n) {
  __shared__ int wsum[16];
  __shared__ int carry_s;
  int lane = threadIdx.x & 63, wv = threadIdx.x >> 6;
  if (threadIdx.x == 0) carry_s = 0;
  __syncthreads();
  for (int base = 0; base < n; base += 1024) {
    int i = base + threadIdx.x;
    int orig = (i < n) ? counts[i] : 0;
    int v = orig;
#pragma unroll
    for (int off = 1; off < 64; off <<= 1) {
      int t = __shfl_up(v, off);
      if (lane >= off) v += t;
    }
    if (lane == 63) wsum[wv] = v;
    __syncthreads();
    int carry = carry_s;
    int wpre = 0;
#pragma unroll
    for (int w = 0; w < 16; w++) wpre += (w < wv) ? wsum[w] : 0;
    int incl = v + wpre;
    if (i < n) offsets[i] = carry + incl - orig;
    __syncthreads();
    if (threadIdx.x == 1023) carry_s = carry + incl;
    __syncthreads();
  }
  if (threadIdx.x == 0) offsets[n] = carry_s;
}

__global__ void k_fill(const int* __restrict__ ei, int E, int ET,
                       const int* __restrict__ offsets, int* __restrict__ cursor,
                       int2* __restrict__ esd) {
  int e = blockIdx.x * blockDim.x + threadIdx.x;
  if (e >= ET) return;
  int s = (e < E) ? ei[e] : (e - E);
  int d = (e < E) ? ei[E + e] : (e - E);
  int pos = offsets[d] + atomicAdd(&cursor[d], 1);
  esd[pos] = make_int2(s, d);
}

// ---------------- W transpose + cast ----------------
__global__ __launch_bounds__(256) void k_transpose_w(const float* __restrict__ W,
                                                     unsigned short* __restrict__ Wt, int K) {
  __shared__ float tile[32][33];
  int tx = threadIdx.x & 31, ty = threadIdx.x >> 5;
  int k0 = blockIdx.x * 32, n0 = blockIdx.y * 32;
#pragma unroll
  for (int r = ty; r < 32; r += 8) tile[r][tx] = W[(size_t)(k0 + r) * HC + n0 + tx];
  __syncthreads();
#pragma unroll
  for (int r = ty; r < 32; r += 8)
    Wt[(size_t)(n0 + r) * K + k0 + tx] = f2bf(tile[tx][r]);
}

// ---------------- cast fp32 -> bf16 ----------------
__global__ void k_cast_bf16(const float* __restrict__ in, unsigned short* __restrict__ out,
                            int n) {
  int i = (blockIdx.x * blockDim.x + threadIdx.x) * 8;
  if (i >= n) return;
  float4 a = *(const float4*)&in[i];
  float4 b = *(const float4*)&in[i + 4];
  ushort4 lo = make_ushort4(f2bf(a.x), f2bf(a.y), f2bf(a.z), f2bf(a.w));
  ushort4 hi = make_ushort4(f2bf(b.x), f2bf(b.y), f2bf(b.z), f2bf(b.w));
  *(ushort4*)&out[i] = lo;
  *(ushort4*)&out[i + 4] = hi;
}

// ---------------- bf16 MFMA GEMM, epilogue writes slice-major hsl[c][n][128] ----
__global__ __launch_bounds__(256) void k_gemm_mfma(const unsigned short* __restrict__ A,
                                                   const unsigned short* __restrict__ Bt,
                                                   unsigned short* __restrict__ hsl, int M,
                                                   int K) {
  __shared__ unsigned short sA[2][128 * 32];
  __shared__ unsigned short sB[2][128 * 32];
  int t = threadIdx.x;
  int lane = t & 63, wv = t >> 6;
  int wr = wv >> 1, wc = wv & 1;
  int row0 = blockIdx.x * 128, col0 = blockIdx.y * 128;
  int l15 = lane & 15, l4 = lane >> 4;

  f32x4 acc[4][4] = {};

  auto stage = [&](unsigned short* sdst, const unsigned short* g, int grow0, int rowmax,
                   int k0) {
#pragma unroll
    for (int q = 0; q < 2; ++q) {
      int r = grow0 + q * 64 + (t >> 2);
      if (r > rowmax) r = rowmax;
      const unsigned short* gp = g + (size_t)r * K + k0 + (t & 3) * 8;
      gload_lds16(gp, sdst + q * 2048 + t * 8);
    }
  };

  int KT = K / 32;
  stage(sA[0], A, row0, M - 1, 0);
  stage(sB[0], Bt, col0, HC - 1, 0);
  int cur = 0;
  for (int kt = 0; kt < KT; ++kt) {
    __syncthreads();
    if (kt + 1 < KT) {
      stage(sA[cur ^ 1], A, row0, M - 1, (kt + 1) * 32);
      stage(sB[cur ^ 1], Bt, col0, HC - 1, (kt + 1) * 32);
    }
    bf16x8 af[4], bfr[4];
#pragma unroll
    for (int i = 0; i < 4; i++)
      af[i] = *(bf16x8*)&sA[cur][(wr * 64 + i * 16 + l15) * 32 + l4 * 8];
#pragma unroll
    for (int j = 0; j < 4; j++)
      bfr[j] = *(bf16x8*)&sB[cur][(wc * 64 + j * 16 + l15) * 32 + l4 * 8];
#pragma unroll
    for (int i = 0; i < 4; i++)
#pragma unroll
      for (int j = 0; j < 4; j++)
        acc[i][j] = __builtin_amdgcn_mfma_f32_16x16x32_bf16(af[i], bfr[j], acc[i][j], 0, 0, 0);
    cur ^= 1;
  }
#pragma unroll
  for (int i = 0; i < 4; i++) {
#pragma unroll
    for (int j = 0; j < 4; j++) {
      int col = col0 + wc * 64 + j * 16 + l15;
      int head = col >> 8;
      int c = (col >> 5) & 7;
      int jj = col & 31;
      size_t sbase = ((size_t)c * M) * 128 + (head << 5) + jj;
#pragma unroll
      for (int r = 0; r < 4; r++) {
        int row = row0 + wr * 64 + i * 16 + l4 * 4 + r;
        if (row < M) hsl[sbase + (size_t)row * 128] = f2bf(acc[i][j][r]);
      }
    }
  }
}

// ---------------- per-node logits from slice-major hsl ----------------
__global__ __launch_bounds__(256) void k_logits(const unsigned short* __restrict__ hsl,
                                                const float* __restrict__ as_,
                                                const float* __restrict__ ad_,
                                                float* __restrict__ es, float* __restrict__ ed,
                                                int M) {
  __shared__ float lds_s[4][64];
  __shared__ float lds_d[4][64];
  int n = blockIdx.x;
  int t = threadIdx.x;
  int c = t >> 5, chunk = t & 31;
  int head = chunk >> 3, q = chunk * 4;
  ushort4 hv = *(const ushort4*)&hsl[((size_t)c * M + n) * 128 + q];
  int ch = head * 256 + c * 32 + (q & 31);
  float4 s4 = *(const float4*)&as_[ch];
  float4 d4 = *(const float4*)&ad_[ch];
  float h0 = bf2f(hv.x), h1 = bf2f(hv.y), h2 = bf2f(hv.z), h3 = bf2f(hv.w);
  float ds = h0 * s4.x + h1 * s4.y + h2 * s4.z + h3 * s4.w;
  float dd = h0 * d4.x + h1 * d4.y + h2 * d4.z + h3 * d4.w;
  int g = c * 8 + (chunk & 7);
  lds_s[head][g] = ds;
  lds_d[head][g] = dd;
  __syncthreads();
  int wv = t >> 6, l = t & 63;
  float vs = lds_s[wv][l];
  float vd = lds_d[wv][l];
#pragma unroll
  for (int off = 32; off; off >>= 1) {
    vs += __shfl_xor(vs, off);
    vd += __shfl_xor(vd, off);
  }
  if (l == 0) {
    es[n * HEADS + wv] = vs;
    ed[n * HEADS + wv] = vd;
  }
}

// ---------------- slot-ordered edge exp ----------------
__global__ void k_edge_exp(const int2* __restrict__ esd, int ET,
                           const float4* __restrict__ es4, const float4* __restrict__ ed4,
                           float4* __restrict__ exs4) {
  int k = blockIdx.x * blockDim.x + threadIdx.x;
  if (k >= ET) return;
  int2 sd = esd[k];
  float4 a = es4[sd.x], b = ed4[sd.y];
  float v0 = a.x + b.x, v1 = a.y + b.y, v2 = a.z + b.z, v3 = a.w + b.w;
  v0 = v0 > 0.f ? v0 : NEG_SLOPE * v0;
  v1 = v1 > 0.f ? v1 : NEG_SLOPE * v1;
  v2 = v2 > 0.f ? v2 : NEG_SLOPE * v2;
  v3 = v3 > 0.f ? v3 : NEG_SLOPE * v3;
  exs4[k] = make_float4(__expf(v0), __expf(v1), __expf(v2), __expf(v3));
}

// ---------------- per-node inverse denom ----------------
__global__ __launch_bounds__(256) void k_denom(const float* __restrict__ exs,
                                               const int* __restrict__ offsets,
                                               float* __restrict__ inva, int N) {
  int lane = threadIdx.x & 63;
  int n = blockIdx.x * 4 + (threadIdx.x >> 6);
  if (n >= N) return;
  int sub = lane >> 2, h = lane & 3;
  int k0 = offsets[n], k1 = offsets[n + 1];
  float sum = 0.f;
  for (int k = k0 + sub; k < k1; k += 16) sum += exs[k * 4 + h];
#pragma unroll
  for (int off = 4; off < 64; off <<= 1) sum += __shfl_xor(sum, off);
  if (lane < 4) inva[n * 4 + h] = 0.25f / (sum + EPSQ);
}

// ---------------- streaming segmented aggregation ----------------
// 16-lane group owns AGG_T contiguous CSR slots of slice c (= blockIdx.x&7,
// XCD round-robin). Per slot: broadcast int2{src,dst} + alpha dword (next-slot
// prefetched) + one coalesced 256B h-burst. On dst change: scale by prefetched
// inva (incl. 0.25 head-mean), 2 shfl head-sums, store (interior node) or
// atomicAdd (range-boundary partial) into zeroed fp32 out.
__global__ __launch_bounds__(256) void k_agg_stream(const unsigned short* __restrict__ hsl,
                                                    const float* __restrict__ exs,
                                                    const float* __restrict__ inva,
                                                    const int2* __restrict__ esd,
                                                    float* __restrict__ outf, int N, int ET,
                                                    int gps) {
  int c = blockIdx.x & 7;
  int gidx = (blockIdx.x >> 3) * 16 + (threadIdx.x >> 4);
  if (gidx >= gps) return;
  int kb = gidx * AGG_T;
  if (kb >= ET) return;
  int ke = kb + AGG_T;
  if (ke > ET) ke = ET;
  int q = threadIdx.x & 15;
  int hq = q >> 2;
  int oc = c * 32 + (q & 3) * 8;
  const unsigned short* sl = hsl + (size_t)c * N * 128;

  float acc[8] = {};
  int2 sd = esd[kb];
  float av = exs[kb * 4 + hq];
  int cur = sd.y;
  float ia = inva[cur * 4 + hq];
  bool first = true;

  auto flush = [&](int dst, bool atomic, float iav) {
    float v[8];
#pragma unroll
    for (int j = 0; j < 8; j++) {
      float tv = acc[j] * iav;
      tv += __shfl_xor(tv, 4);
      tv += __shfl_xor(tv, 8);
      v[j] = tv;
    }
    if (q < 4) {
      float* op = &outf[(size_t)dst * CH + oc];
      if (atomic) {
#pragma unroll
        for (int j = 0; j < 8; j++) atomicAdd(&op[j], v[j]);
      } else {
        *(float4*)op = make_float4(v[0], v[1], v[2], v[3]);
        *(float4*)(op + 4) = make_float4(v[4], v[5], v[6], v[7]);
      }
    }
  };

  for (int k = kb; k < ke; ++k) {
    int kn = (k + 1 < ke) ? k + 1 : k;
    int2 sd_n = esd[kn];
    float av_n = exs[kn * 4 + hq];
    bf16x8 hv = *(const bf16x8*)&sl[(size_t)sd.x * 128 + q * 8];
    if (sd.y != cur) {
      flush(cur, first, ia);
      first = false;
#pragma unroll
      for (int j = 0; j < 8; j++) acc[j] = 0.f;
      cur = sd.y;
      ia = inva[cur * 4 + hq];
    }
#pragma unroll
    for (int j = 0; j < 8; j++) acc[j] += av * bf2f((unsigned short)hv[j]);
    sd = sd_n;
    av = av_n;
  }
  flush(cur, true, ia);  // tail may extend into next range -> atomic
}

// ---------------- bias + cast epilogue ----------------
__global__ void k_bias(const float* __restrict__ outf, const float* __restrict__ bias,
                       unsigned short* __restrict__ obf, float* __restrict__ of, int total) {
  int i = (blockIdx.x * blockDim.x + threadIdx.x) * 4;
  if (i >= total) return;
  float4 v = *(const float4*)&outf[i];
  float4 b = *(const float4*)&bias[i & 255];
  v.x += b.x;
  v.y += b.y;
  v.z += b.z;
  v.w += b.w;
  if (of) {
    *(float4*)&of[i] = v;
  } else {
    ushort4 o = make_ushort4(f2bf(v.x), f2bf(v.y), f2bf(v.z), f2bf(v.w));
    *(ushort4*)&obf[i] = o;
  }
}

extern "C" void kernel_launch(void* const* d_in, const int* in_sizes, int n_in,
                              void* d_out, int out_size, void* d_ws, size_t ws_size,
                              hipStream_t stream) {
  const float* x = (const float*)d_in[0];
  const int* ei = (const int*)d_in[1];
  const float* W[3] = {(const float*)d_in[2], (const float*)d_in[6], (const float*)d_in[10]};
  const float* AS[3] = {(const float*)d_in[3], (const float*)d_in[7], (const float*)d_in[11]};
  const float* AD[3] = {(const float*)d_in[4], (const float*)d_in[8], (const float*)d_in[12]};
  const float* BI[3] = {(const float*)d_in[5], (const float*)d_in[9], (const float*)d_in[13]};
  const int N = in_sizes[0] / 512;
  const int E = in_sizes[1] / 2;
  const int ET = E + N;
  const int Kd[3] = {512, 256, 256};

  char* p = (char*)d_ws;
  auto alloc = [&](size_t bytes) {
    char* r = p;
    p += (bytes + 255) & ~(size_t)255;
    return (void*)r;
  };
  unsigned short* hsl = (unsigned short*)alloc((size_t)NSLICE * N * 128 * 2);
  unsigned short* axb = (unsigned short*)alloc((size_t)N * 512 * 2);
  unsigned short* actbf = (unsigned short*)alloc((size_t)N * CH * 2);
  float* outf = (float*)alloc((size_t)N * CH * 4);
  unsigned short* Wt[3];
  for (int i = 0; i < 3; i++) Wt[i] = (unsigned short*)alloc((size_t)HC * Kd[i] * 2);
  float* es = (float*)alloc((size_t)N * HEADS * 4);
  float* ed = (float*)alloc((size_t)N * HEADS * 4);
  float* exs = (float*)alloc((size_t)ET * HEADS * 4);
  float* inva = (float*)alloc((size_t)N * HEADS * 4);
  int* offsets = (int*)alloc((size_t)(N + 1) * 4);
  int* cursor = (int*)alloc((size_t)N * 4);
  int2* esd = (int2*)alloc((size_t)ET * 8);

  // ---- CSR build (shared by all 3 layers) ----
  hipMemsetAsync(cursor, 0, (size_t)N * 4, stream);
  k_count<<<cdiv(ET, 256), 256, 0, stream>>>(ei, E, ET, cursor);
  k_scan<<<1, 1024, 0, stream>>>(cursor, offsets, N);
  hipMemsetAsync(cursor, 0, (size_t)N * 4, stream);
  k_fill<<<cdiv(ET, 256), 256, 0, stream>>>(ei, E, ET, offsets, cursor, esd);

  // ---- weight transpose+cast, input cast ----
  for (int i = 0; i < 3; i++)
    k_transpose_w<<<dim3(Kd[i] / 32, HC / 32), 256, 0, stream>>>(W[i], Wt[i], Kd[i]);
  k_cast_bf16<<<cdiv(N * 512, 8 * 256), 256, 0, stream>>>(x, axb, N * 512);

  const unsigned short* ain = axb;
  int gps = cdiv(ET, AGG_T);                 // groups per slice
  int aggGrid = cdiv(gps, 16) * 8;           // 16 groups per block, x8 slices
  for (int layer = 0; layer < 3; ++layer) {
    int K = Kd[layer];
    k_gemm_mfma<<<dim3(cdiv(N, 128), HC / 128), 256, 0, stream>>>(ain, Wt[layer], hsl, N, K);
    k_logits<<<N, 256, 0, stream>>>(hsl, AS[layer], AD[layer], es, ed, N);
    k_edge_exp<<<cdiv(ET, 256), 256, 0, stream>>>(esd, ET, (const float4*)es,
                                                  (const float4*)ed, (float4*)exs);
    k_denom<<<cdiv(N, 4), 256, 0, stream>>>(exs, offsets, inva, N);
    hipMemsetAsync(outf, 0, (size_t)N * CH * 4, stream);
    k_agg_stream<<<aggGrid, 256, 0, stream>>>(hsl, exs, inva, esd, outf, N, ET, gps);
    if (layer < 2) {
      k_bias<<<cdiv(N * CH / 4, 256), 256, 0, stream>>>(outf, BI[layer], actbf,
                                                        (float*)nullptr, N * CH);
    } else {
      k_bias<<<cdiv(N * CH / 4, 256), 256, 0, stream>>>(outf, BI[layer],
                                                        (unsigned short*)nullptr,
                                                        (float*)d_out, N * CH);
    }
    ain = actbf;
  }
}

// Round 11
// 301.603 us; speedup vs baseline: 1.4948x; 1.4948x over previous
//
#include <hip/hip_runtime.h>
#include <math.h>

#define HEADS 4
#define CH 256
#define HC 1024
#define NSLICE 8
#define NEG_SLOPE 0.2f
#define EPSQ 1e-16f

typedef __attribute__((ext_vector_type(8))) short bf16x8;
typedef __attribute__((ext_vector_type(4))) float f32x4;

static inline int cdiv(int a, int b) { return (a + b - 1) / b; }

__device__ __forceinline__ unsigned short f2bf(float f) {
  unsigned u = __float_as_uint(f);
  u += 0x7FFFu + ((u >> 16) & 1u);  // RNE
  return (unsigned short)(u >> 16);
}
__device__ __forceinline__ float bf2f(unsigned short s) {
  return __uint_as_float(((unsigned)s) << 16);
}
__device__ __forceinline__ float bf_lo(unsigned p) {
  return __uint_as_float(p << 16);
}
__device__ __forceinline__ float bf_hi(unsigned p) {
  return __uint_as_float(p & 0xFFFF0000u);
}
__device__ __forceinline__ void gload_lds16(const void* g, void* l) {
  __builtin_amdgcn_global_load_lds((const __attribute__((address_space(1))) void*)g,
                                   (__attribute__((address_space(3))) void*)l, 16, 0, 0);
}

// ---------------- CSR build ----------------
__global__ void k_count(const int* __restrict__ ei, int E, int ET, int* __restrict__ cnt) {
  int e = blockIdx.x * blockDim.x + threadIdx.x;
  if (e >= ET) return;
  int d = (e < E) ? ei[E + e] : (e - E);
  atomicAdd(&cnt[d], 1);
}

__global__ __launch_bounds__(1024) void k_scan(const int* __restrict__ counts,
                                               int* __restrict__ offsets, int n) {
  __shared__ int wsum[16];
  __shared__ int carry_s;
  int lane = threadIdx.x & 63, wv = threadIdx.x >> 6;
  if (threadIdx.x == 0) carry_s = 0;
  __syncthreads();
  for (int base = 0; base < n; base += 1024) {
    int i = base + threadIdx.x;
    int orig = (i < n) ? counts[i] : 0;
    int v = orig;
#pragma unroll
    for (int off = 1; off < 64; off <<= 1) {
      int t = __shfl_up(v, off);
      if (lane >= off) v += t;
    }
    if (lane == 63) wsum[wv] = v;
    __syncthreads();
    int carry = carry_s;
    int wpre = 0;
#pragma unroll
    for (int w = 0; w < 16; w++) wpre += (w < wv) ? wsum[w] : 0;
    int incl = v + wpre;
    if (i < n) offsets[i] = carry + incl - orig;
    __syncthreads();
    if (threadIdx.x == 1023) carry_s = carry + incl;
    __syncthreads();
  }
  if (threadIdx.x == 0) offsets[n] = carry_s;
}

__global__ void k_fill(const int* __restrict__ ei, int E, int ET,
                       const int* __restrict__ offsets, int* __restrict__ cursor,
                       int2* __restrict__ esd) {
  int e = blockIdx.x * blockDim.x + threadIdx.x;
  if (e >= ET) return;
  int s = (e < E) ? ei[e] : (e - E);
  int d = (e < E) ? ei[E + e] : (e - E);
  int pos = offsets[d] + atomicAdd(&cursor[d], 1);
  esd[pos] = make_int2(s, d);
}

// ---------------- W transpose + cast ----------------
__global__ __launch_bounds__(256) void k_transpose_w(const float* __restrict__ W,
                                                     unsigned short* __restrict__ Wt, int K) {
  __shared__ float tile[32][33];
  int tx = threadIdx.x & 31, ty = threadIdx.x >> 5;
  int k0 = blockIdx.x * 32, n0 = blockIdx.y * 32;
#pragma unroll
  for (int r = ty; r < 32; r += 8) tile[r][tx] = W[(size_t)(k0 + r) * HC + n0 + tx];
  __syncthreads();
#pragma unroll
  for (int r = ty; r < 32; r += 8)
    Wt[(size_t)(n0 + r) * K + k0 + tx] = f2bf(tile[tx][r]);
}

// ---------------- cast fp32 -> bf16 ----------------
__global__ void k_cast_bf16(const float* __restrict__ in, unsigned short* __restrict__ out,
                            int n) {
  int i = (blockIdx.x * blockDim.x + threadIdx.x) * 8;
  if (i >= n) return;
  float4 a = *(const float4*)&in[i];
  float4 b = *(const float4*)&in[i + 4];
  ushort4 lo = make_ushort4(f2bf(a.x), f2bf(a.y), f2bf(a.z), f2bf(a.w));
  ushort4 hi = make_ushort4(f2bf(b.x), f2bf(b.y), f2bf(b.z), f2bf(b.w));
  *(ushort4*)&out[i] = lo;
  *(ushort4*)&out[i + 4] = hi;
}

// ---------------- bf16 MFMA GEMM, epilogue writes slice-major hsl[c][n][128] ----
__global__ __launch_bounds__(256) void k_gemm_mfma(const unsigned short* __restrict__ A,
                                                   const unsigned short* __restrict__ Bt,
                                                   unsigned short* __restrict__ hsl, int M,
                                                   int K) {
  __shared__ unsigned short sA[2][128 * 32];
  __shared__ unsigned short sB[2][128 * 32];
  int t = threadIdx.x;
  int lane = t & 63, wv = t >> 6;
  int wr = wv >> 1, wc = wv & 1;
  int row0 = blockIdx.x * 128, col0 = blockIdx.y * 128;
  int l15 = lane & 15, l4 = lane >> 4;

  f32x4 acc[4][4] = {};

  auto stage = [&](unsigned short* sdst, const unsigned short* g, int grow0, int rowmax,
                   int k0) {
#pragma unroll
    for (int q = 0; q < 2; ++q) {
      int r = grow0 + q * 64 + (t >> 2);
      if (r > rowmax) r = rowmax;
      const unsigned short* gp = g + (size_t)r * K + k0 + (t & 3) * 8;
      gload_lds16(gp, sdst + q * 2048 + t * 8);
    }
  };

  int KT = K / 32;
  stage(sA[0], A, row0, M - 1, 0);
  stage(sB[0], Bt, col0, HC - 1, 0);
  int cur = 0;
  for (int kt = 0; kt < KT; ++kt) {
    __syncthreads();
    if (kt + 1 < KT) {
      stage(sA[cur ^ 1], A, row0, M - 1, (kt + 1) * 32);
      stage(sB[cur ^ 1], Bt, col0, HC - 1, (kt + 1) * 32);
    }
    bf16x8 af[4], bfr[4];
#pragma unroll
    for (int i = 0; i < 4; i++)
      af[i] = *(bf16x8*)&sA[cur][(wr * 64 + i * 16 + l15) * 32 + l4 * 8];
#pragma unroll
    for (int j = 0; j < 4; j++)
      bfr[j] = *(bf16x8*)&sB[cur][(wc * 64 + j * 16 + l15) * 32 + l4 * 8];
#pragma unroll
    for (int i = 0; i < 4; i++)
#pragma unroll
      for (int j = 0; j < 4; j++)
        acc[i][j] = __builtin_amdgcn_mfma_f32_16x16x32_bf16(af[i], bfr[j], acc[i][j], 0, 0, 0);
    cur ^= 1;
  }
#pragma unroll
  for (int i = 0; i < 4; i++) {
#pragma unroll
    for (int j = 0; j < 4; j++) {
      int col = col0 + wc * 64 + j * 16 + l15;
      int head = col >> 8;
      int c = (col >> 5) & 7;
      int jj = col & 31;
      size_t sbase = ((size_t)c * M) * 128 + (head << 5) + jj;
#pragma unroll
      for (int r = 0; r < 4; r++) {
        int row = row0 + wr * 64 + i * 16 + l4 * 4 + r;
        if (row < M) hsl[sbase + (size_t)row * 128] = f2bf(acc[i][j][r]);
      }
    }
  }
}

// ---------------- per-node logits from slice-major hsl ----------------
__global__ __launch_bounds__(256) void k_logits(const unsigned short* __restrict__ hsl,
                                                const float* __restrict__ as_,
                                                const float* __restrict__ ad_,
                                                float* __restrict__ es, float* __restrict__ ed,
                                                int M) {
  __shared__ float lds_s[4][64];
  __shared__ float lds_d[4][64];
  int n = blockIdx.x;
  int t = threadIdx.x;
  int c = t >> 5, chunk = t & 31;
  int head = chunk >> 3, q = chunk * 4;
  ushort4 hv = *(const ushort4*)&hsl[((size_t)c * M + n) * 128 + q];
  int ch = head * 256 + c * 32 + (q & 31);
  float4 s4 = *(const float4*)&as_[ch];
  float4 d4 = *(const float4*)&ad_[ch];
  float h0 = bf2f(hv.x), h1 = bf2f(hv.y), h2 = bf2f(hv.z), h3 = bf2f(hv.w);
  float ds = h0 * s4.x + h1 * s4.y + h2 * s4.z + h3 * s4.w;
  float dd = h0 * d4.x + h1 * d4.y + h2 * d4.z + h3 * d4.w;
  int g = c * 8 + (chunk & 7);
  lds_s[head][g] = ds;
  lds_d[head][g] = dd;
  __syncthreads();
  int wv = t >> 6, l = t & 63;
  float vs = lds_s[wv][l];
  float vd = lds_d[wv][l];
#pragma unroll
  for (int off = 32; off; off >>= 1) {
    vs += __shfl_xor(vs, off);
    vd += __shfl_xor(vd, off);
  }
  if (l == 0) {
    es[n * HEADS + wv] = vs;
    ed[n * HEADS + wv] = vd;
  }
}

// ---------------- slot-ordered edge exp ----------------
__global__ void k_edge_exp(const int2* __restrict__ esd, int ET,
                           const float4* __restrict__ es4, const float4* __restrict__ ed4,
                           float4* __restrict__ exs4) {
  int k = blockIdx.x * blockDim.x + threadIdx.x;
  if (k >= ET) return;
  int2 sd = esd[k];
  float4 a = es4[sd.x], b = ed4[sd.y];
  float v0 = a.x + b.x, v1 = a.y + b.y, v2 = a.z + b.z, v3 = a.w + b.w;
  v0 = v0 > 0.f ? v0 : NEG_SLOPE * v0;
  v1 = v1 > 0.f ? v1 : NEG_SLOPE * v1;
  v2 = v2 > 0.f ? v2 : NEG_SLOPE * v2;
  v3 = v3 > 0.f ? v3 : NEG_SLOPE * v3;
  exs4[k] = make_float4(__expf(v0), __expf(v1), __expf(v2), __expf(v3));
}

// ---------------- per-node inverse denom ----------------
__global__ __launch_bounds__(256) void k_denom(const float* __restrict__ exs,
                                               const int* __restrict__ offsets,
                                               float* __restrict__ inva, int N) {
  int lane = threadIdx.x & 63;
  int n = blockIdx.x * 4 + (threadIdx.x >> 6);
  if (n >= N) return;
  int sub = lane >> 2, h = lane & 3;
  int k0 = offsets[n], k1 = offsets[n + 1];
  float sum = 0.f;
  for (int k = k0 + sub; k < k1; k += 16) sum += exs[k * 4 + h];
#pragma unroll
  for (int off = 4; off < 64; off <<= 1) sum += __shfl_xor(sum, off);
  if (lane < 4) inva[n * 4 + h] = 0.25f / (sum + EPSQ);
}

// ---------------- XCD-sliced aggregation, 2 nodes per wave ----------------
// Wave = 2 half-waves of 32 lanes; half h handles node pairbase+h of slice
// c = blockIdx&7 (XCD round-robin, 2.5MB L2-resident table). Lane owns 8B
// (4 ch, one head) of the 256B slice row. Per iteration each half processes
// one edge: clamped esd.x broadcast + alpha dword (cndmask past degree) +
// dwordx2 h-burst -> every instruction serves TWO edge-visits. Head-reduce
// = shfl_xor 8,16 (stays within half); exclusive writes, bias folded.
__global__ __launch_bounds__(256) void k_aggregate(const unsigned short* __restrict__ hsl,
                                                   const float* __restrict__ exs,
                                                   const float* __restrict__ inva,
                                                   const int* __restrict__ offsets,
                                                   const int2* __restrict__ esd,
                                                   const float* __restrict__ bias,
                                                   float* __restrict__ xout,
                                                   unsigned short* __restrict__ xout_bf,
                                                   int N) {
  int c = blockIdx.x & 7;
  int pairbase = (blockIdx.x >> 3) * 8 + (threadIdx.x >> 6) * 2;
  if (pairbase >= N) return;
  int lane = threadIdx.x & 63;
  int l32 = lane & 31;
  int n = pairbase + (lane >> 5);
  bool valid = n < N;
  if (!valid) n = N - 1;
  int hq = l32 >> 3;
  const unsigned short* sl = hsl + (size_t)c * N * 128;
  int k0 = offsets[n], k1 = offsets[n + 1];
  int deg = k1 - k0;
  int kmax = k1 - 1;
  int dmax = deg;
  {
    int other = __shfl_xor(deg, 32);
    dmax = deg > other ? deg : other;
  }
  float acc0 = 0.f, acc1 = 0.f, acc2 = 0.f, acc3 = 0.f;
#pragma unroll 2
  for (int i = 0; i < dmax; ++i) {
    int k = k0 + i;
    k = k < kmax ? k : kmax;
    int s = esd[k].x;
    float a = exs[k * 4 + hq];
    a = (i < deg) ? a : 0.f;
    uint2 p = *(const uint2*)&sl[((size_t)s << 7) + l32 * 4];
    acc0 += a * bf_lo(p.x);
    acc1 += a * bf_hi(p.x);
    acc2 += a * bf_lo(p.y);
    acc3 += a * bf_hi(p.y);
  }
  float ia = inva[n * 4 + hq];  // 0.25/denom (head-mean folded)
  acc0 *= ia;
  acc1 *= ia;
  acc2 *= ia;
  acc3 *= ia;
  // head reduce: lanes l32, l32^8, l32^16, l32^24 hold the 4 heads (stays in half)
  acc0 += __shfl_xor(acc0, 8);
  acc0 += __shfl_xor(acc0, 16);
  acc1 += __shfl_xor(acc1, 8);
  acc1 += __shfl_xor(acc1, 16);
  acc2 += __shfl_xor(acc2, 8);
  acc2 += __shfl_xor(acc2, 16);
  acc3 += __shfl_xor(acc3, 8);
  acc3 += __shfl_xor(acc3, 16);
  if (valid && l32 < 8) {
    int oc = c * 32 + l32 * 4;
    float v0 = acc0 + bias[oc + 0];
    float v1 = acc1 + bias[oc + 1];
    float v2 = acc2 + bias[oc + 2];
    float v3 = acc3 + bias[oc + 3];
    if (xout) {
      *(float4*)&xout[(size_t)n * CH + oc] = make_float4(v0, v1, v2, v3);
    } else {
      ushort4 o = make_ushort4(f2bf(v0), f2bf(v1), f2bf(v2), f2bf(v3));
      *(ushort4*)&xout_bf[(size_t)n * CH + oc] = o;
    }
  }
}

extern "C" void kernel_launch(void* const* d_in, const int* in_sizes, int n_in,
                              void* d_out, int out_size, void* d_ws, size_t ws_size,
                              hipStream_t stream) {
  const float* x = (const float*)d_in[0];
  const int* ei = (const int*)d_in[1];
  const float* W[3] = {(const float*)d_in[2], (const float*)d_in[6], (const float*)d_in[10]};
  const float* AS[3] = {(const float*)d_in[3], (const float*)d_in[7], (const float*)d_in[11]};
  const float* AD[3] = {(const float*)d_in[4], (const float*)d_in[8], (const float*)d_in[12]};
  const float* BI[3] = {(const float*)d_in[5], (const float*)d_in[9], (const float*)d_in[13]};
  const int N = in_sizes[0] / 512;
  const int E = in_sizes[1] / 2;
  const int ET = E + N;
  const int Kd[3] = {512, 256, 256};

  char* p = (char*)d_ws;
  auto alloc = [&](size_t bytes) {
    char* r = p;
    p += (bytes + 255) & ~(size_t)255;
    return (void*)r;
  };
  unsigned short* hsl = (unsigned short*)alloc((size_t)NSLICE * N * 128 * 2);
  unsigned short* axb = (unsigned short*)alloc((size_t)N * 512 * 2);
  unsigned short* actbf = (unsigned short*)alloc((size_t)N * CH * 2);
  unsigned short* Wt[3];
  for (int i = 0; i < 3; i++) Wt[i] = (unsigned short*)alloc((size_t)HC * Kd[i] * 2);
  float* es = (float*)alloc((size_t)N * HEADS * 4);
  float* ed = (float*)alloc((size_t)N * HEADS * 4);
  float* exs = (float*)alloc((size_t)ET * HEADS * 4);
  float* inva = (float*)alloc((size_t)N * HEADS * 4);
  int* offsets = (int*)alloc((size_t)(N + 1) * 4);
  int* cursor = (int*)alloc((size_t)N * 4);
  int2* esd = (int2*)alloc((size_t)ET * 8);

  // ---- CSR build (shared by all 3 layers) ----
  hipMemsetAsync(cursor, 0, (size_t)N * 4, stream);
  k_count<<<cdiv(ET, 256), 256, 0, stream>>>(ei, E, ET, cursor);
  k_scan<<<1, 1024, 0, stream>>>(cursor, offsets, N);
  hipMemsetAsync(cursor, 0, (size_t)N * 4, stream);
  k_fill<<<cdiv(ET, 256), 256, 0, stream>>>(ei, E, ET, offsets, cursor, esd);

  // ---- weight transpose+cast, input cast ----
  for (int i = 0; i < 3; i++)
    k_transpose_w<<<dim3(Kd[i] / 32, HC / 32), 256, 0, stream>>>(W[i], Wt[i], Kd[i]);
  k_cast_bf16<<<cdiv(N * 512, 8 * 256), 256, 0, stream>>>(x, axb, N * 512);

  const unsigned short* ain = axb;
  int aggGrid = cdiv(N, 8) * 8;  // 4 waves/block x 2 nodes/wave, x8 slices
  for (int layer = 0; layer < 3; ++layer) {
    int K = Kd[layer];
    k_gemm_mfma<<<dim3(cdiv(N, 128), HC / 128), 256, 0, stream>>>(ain, Wt[layer], hsl, N, K);
    k_logits<<<N, 256, 0, stream>>>(hsl, AS[layer], AD[layer], es, ed, N);
    k_edge_exp<<<cdiv(ET, 256), 256, 0, stream>>>(esd, ET, (const float4*)es,
                                                  (const float4*)ed, (float4*)exs);
    k_denom<<<cdiv(N, 4), 256, 0, stream>>>(exs, offsets, inva, N);
    if (layer < 2) {
      k_aggregate<<<aggGrid, 256, 0, stream>>>(hsl, exs, inva, offsets, esd, BI[layer],
                                               (float*)nullptr, actbf, N);
    } else {
      k_aggregate<<<aggGrid, 256, 0, stream>>>(hsl, exs, inva, offsets, esd, BI[layer],
                                               (float*)d_out, (unsigned short*)nullptr, N);
    }
    ain = actbf;
  }
}

// Round 12
// 290.141 us; speedup vs baseline: 1.5538x; 1.0395x over previous
//
#include <hip/hip_runtime.h>
#include <math.h>

#define HEADS 4
#define CH 256
#define HC 1024
#define NSLICE 8
#define NEG_SLOPE 0.2f
#define EPSQ 1e-16f
#define MAXS 320  // staged CSR slots per block (4 nodes, max degree ~45 -> <=180 typ.)

typedef __attribute__((ext_vector_type(8))) short bf16x8;
typedef __attribute__((ext_vector_type(4))) float f32x4;

static inline int cdiv(int a, int b) { return (a + b - 1) / b; }

__device__ __forceinline__ unsigned short f2bf(float f) {
  unsigned u = __float_as_uint(f);
  u += 0x7FFFu + ((u >> 16) & 1u);  // RNE
  return (unsigned short)(u >> 16);
}
__device__ __forceinline__ float bf2f(unsigned short s) {
  return __uint_as_float(((unsigned)s) << 16);
}
__device__ __forceinline__ void gload_lds16(const void* g, void* l) {
  __builtin_amdgcn_global_load_lds((const __attribute__((address_space(1))) void*)g,
                                   (__attribute__((address_space(3))) void*)l, 16, 0, 0);
}

// ---------------- CSR build ----------------
__global__ void k_count(const int* __restrict__ ei, int E, int ET, int* __restrict__ cnt) {
  int e = blockIdx.x * blockDim.x + threadIdx.x;
  if (e >= ET) return;
  int d = (e < E) ? ei[E + e] : (e - E);
  atomicAdd(&cnt[d], 1);
}

__global__ __launch_bounds__(1024) void k_scan(const int* __restrict__ counts,
                                               int* __restrict__ offsets, int n) {
  __shared__ int wsum[16];
  __shared__ int carry_s;
  int lane = threadIdx.x & 63, wv = threadIdx.x >> 6;
  if (threadIdx.x == 0) carry_s = 0;
  __syncthreads();
  for (int base = 0; base < n; base += 1024) {
    int i = base + threadIdx.x;
    int orig = (i < n) ? counts[i] : 0;
    int v = orig;
#pragma unroll
    for (int off = 1; off < 64; off <<= 1) {
      int t = __shfl_up(v, off);
      if (lane >= off) v += t;
    }
    if (lane == 63) wsum[wv] = v;
    __syncthreads();
    int carry = carry_s;
    int wpre = 0;
#pragma unroll
    for (int w = 0; w < 16; w++) wpre += (w < wv) ? wsum[w] : 0;
    int incl = v + wpre;
    if (i < n) offsets[i] = carry + incl - orig;
    __syncthreads();
    if (threadIdx.x == 1023) carry_s = carry + incl;
    __syncthreads();
  }
  if (threadIdx.x == 0) offsets[n] = carry_s;
}

__global__ void k_fill(const int* __restrict__ ei, int E, int ET,
                       const int* __restrict__ offsets, int* __restrict__ cursor,
                       int2* __restrict__ esd) {
  int e = blockIdx.x * blockDim.x + threadIdx.x;
  if (e >= ET) return;
  int s = (e < E) ? ei[e] : (e - E);
  int d = (e < E) ? ei[E + e] : (e - E);
  int pos = offsets[d] + atomicAdd(&cursor[d], 1);
  esd[pos] = make_int2(s, d);
}

// ---------------- W transpose + cast ----------------
__global__ __launch_bounds__(256) void k_transpose_w(const float* __restrict__ W,
                                                     unsigned short* __restrict__ Wt, int K) {
  __shared__ float tile[32][33];
  int tx = threadIdx.x & 31, ty = threadIdx.x >> 5;
  int k0 = blockIdx.x * 32, n0 = blockIdx.y * 32;
#pragma unroll
  for (int r = ty; r < 32; r += 8) tile[r][tx] = W[(size_t)(k0 + r) * HC + n0 + tx];
  __syncthreads();
#pragma unroll
  for (int r = ty; r < 32; r += 8)
    Wt[(size_t)(n0 + r) * K + k0 + tx] = f2bf(tile[tx][r]);
}

// ---------------- cast fp32 -> bf16 ----------------
__global__ void k_cast_bf16(const float* __restrict__ in, unsigned short* __restrict__ out,
                            int n) {
  int i = (blockIdx.x * blockDim.x + threadIdx.x) * 8;
  if (i >= n) return;
  float4 a = *(const float4*)&in[i];
  float4 b = *(const float4*)&in[i + 4];
  ushort4 lo = make_ushort4(f2bf(a.x), f2bf(a.y), f2bf(a.z), f2bf(a.w));
  ushort4 hi = make_ushort4(f2bf(b.x), f2bf(b.y), f2bf(b.z), f2bf(b.w));
  *(ushort4*)&out[i] = lo;
  *(ushort4*)&out[i + 4] = hi;
}

// ---------------- bf16 MFMA GEMM, epilogue writes slice-major hsl[c][n][128] ----
__global__ __launch_bounds__(256) void k_gemm_mfma(const unsigned short* __restrict__ A,
                                                   const unsigned short* __restrict__ Bt,
                                                   unsigned short* __restrict__ hsl, int M,
                                                   int K) {
  __shared__ unsigned short sA[2][128 * 32];
  __shared__ unsigned short sB[2][128 * 32];
  int t = threadIdx.x;
  int lane = t & 63, wv = t >> 6;
  int wr = wv >> 1, wc = wv & 1;
  int row0 = blockIdx.x * 128, col0 = blockIdx.y * 128;
  int l15 = lane & 15, l4 = lane >> 4;

  f32x4 acc[4][4] = {};

  auto stage = [&](unsigned short* sdst, const unsigned short* g, int grow0, int rowmax,
                   int k0) {
#pragma unroll
    for (int q = 0; q < 2; ++q) {
      int r = grow0 + q * 64 + (t >> 2);
      if (r > rowmax) r = rowmax;
      const unsigned short* gp = g + (size_t)r * K + k0 + (t & 3) * 8;
      gload_lds16(gp, sdst + q * 2048 + t * 8);
    }
  };

  int KT = K / 32;
  stage(sA[0], A, row0, M - 1, 0);
  stage(sB[0], Bt, col0, HC - 1, 0);
  int cur = 0;
  for (int kt = 0; kt < KT; ++kt) {
    __syncthreads();
    if (kt + 1 < KT) {
      stage(sA[cur ^ 1], A, row0, M - 1, (kt + 1) * 32);
      stage(sB[cur ^ 1], Bt, col0, HC - 1, (kt + 1) * 32);
    }
    bf16x8 af[4], bfr[4];
#pragma unroll
    for (int i = 0; i < 4; i++)
      af[i] = *(bf16x8*)&sA[cur][(wr * 64 + i * 16 + l15) * 32 + l4 * 8];
#pragma unroll
    for (int j = 0; j < 4; j++)
      bfr[j] = *(bf16x8*)&sB[cur][(wc * 64 + j * 16 + l15) * 32 + l4 * 8];
#pragma unroll
    for (int i = 0; i < 4; i++)
#pragma unroll
      for (int j = 0; j < 4; j++)
        acc[i][j] = __builtin_amdgcn_mfma_f32_16x16x32_bf16(af[i], bfr[j], acc[i][j], 0, 0, 0);
    cur ^= 1;
  }
#pragma unroll
  for (int i = 0; i < 4; i++) {
#pragma unroll
    for (int j = 0; j < 4; j++) {
      int col = col0 + wc * 64 + j * 16 + l15;
      int head = col >> 8;
      int c = (col >> 5) & 7;
      int jj = col & 31;
      size_t sbase = ((size_t)c * M) * 128 + (head << 5) + jj;
#pragma unroll
      for (int r = 0; r < 4; r++) {
        int row = row0 + wr * 64 + i * 16 + l4 * 4 + r;
        if (row < M) hsl[sbase + (size_t)row * 128] = f2bf(acc[i][j][r]);
      }
    }
  }
}

// ---------------- per-node logits from slice-major hsl ----------------
__global__ __launch_bounds__(256) void k_logits(const unsigned short* __restrict__ hsl,
                                                const float* __restrict__ as_,
                                                const float* __restrict__ ad_,
                                                float* __restrict__ es, float* __restrict__ ed,
                                                int M) {
  __shared__ float lds_s[4][64];
  __shared__ float lds_d[4][64];
  int n = blockIdx.x;
  int t = threadIdx.x;
  int c = t >> 5, chunk = t & 31;
  int head = chunk >> 3, q = chunk * 4;
  ushort4 hv = *(const ushort4*)&hsl[((size_t)c * M + n) * 128 + q];
  int ch = head * 256 + c * 32 + (q & 31);
  float4 s4 = *(const float4*)&as_[ch];
  float4 d4 = *(const float4*)&ad_[ch];
  float h0 = bf2f(hv.x), h1 = bf2f(hv.y), h2 = bf2f(hv.z), h3 = bf2f(hv.w);
  float ds = h0 * s4.x + h1 * s4.y + h2 * s4.z + h3 * s4.w;
  float dd = h0 * d4.x + h1 * d4.y + h2 * d4.z + h3 * d4.w;
  int g = c * 8 + (chunk & 7);
  lds_s[head][g] = ds;
  lds_d[head][g] = dd;
  __syncthreads();
  int wv = t >> 6, l = t & 63;
  float vs = lds_s[wv][l];
  float vd = lds_d[wv][l];
#pragma unroll
  for (int off = 32; off; off >>= 1) {
    vs += __shfl_xor(vs, off);
    vd += __shfl_xor(vd, off);
  }
  if (l == 0) {
    es[n * HEADS + wv] = vs;
    ed[n * HEADS + wv] = vd;
  }
}

// ---------------- slot-ordered edge exp ----------------
__global__ void k_edge_exp(const int2* __restrict__ esd, int ET,
                           const float4* __restrict__ es4, const float4* __restrict__ ed4,
                           float4* __restrict__ exs4) {
  int k = blockIdx.x * blockDim.x + threadIdx.x;
  if (k >= ET) return;
  int2 sd = esd[k];
  float4 a = es4[sd.x], b = ed4[sd.y];
  float v0 = a.x + b.x, v1 = a.y + b.y, v2 = a.z + b.z, v3 = a.w + b.w;
  v0 = v0 > 0.f ? v0 : NEG_SLOPE * v0;
  v1 = v1 > 0.f ? v1 : NEG_SLOPE * v1;
  v2 = v2 > 0.f ? v2 : NEG_SLOPE * v2;
  v3 = v3 > 0.f ? v3 : NEG_SLOPE * v3;
  exs4[k] = make_float4(__expf(v0), __expf(v1), __expf(v2), __expf(v3));
}

// ---------------- per-node inverse denom ----------------
__global__ __launch_bounds__(256) void k_denom(const float* __restrict__ exs,
                                               const int* __restrict__ offsets,
                                               float* __restrict__ inva, int N) {
  int lane = threadIdx.x & 63;
  int n = blockIdx.x * 4 + (threadIdx.x >> 6);
  if (n >= N) return;
  int sub = lane >> 2, h = lane & 3;
  int k0 = offsets[n], k1 = offsets[n + 1];
  float sum = 0.f;
  for (int k = k0 + sub; k < k1; k += 16) sum += exs[k * 4 + h];
#pragma unroll
  for (int off = 4; off < 64; off <<= 1) sum += __shfl_xor(sum, off);
  if (lane < 4) inva[n * 4 + h] = 0.25f / (sum + EPSQ);
}

// ---------------- XCD-sliced aggregation (R8 grouping) + LDS metadata ----------------
// Block = 4 waves = 4 consecutive nodes of slice c (blockIdx&7 -> XCD). Block's
// CSR slots are one contiguous range: stage {alpha[4], src} per slot into LDS
// once, barrier, then the inner loop's metadata reads are 1-instr 32-bit
// ds_read_b32 (conflict-free: 16 (g,hq) combos -> 16 distinct banks). Only the
// h-burst remains a global stream. Wave = 4 groups x 16 lanes; group g walks
// its node's edges at stride 4; lane owns 16B (8ch) of the 256B slice row.
__global__ __launch_bounds__(256) void k_aggregate(const unsigned short* __restrict__ hsl,
                                                   const float4* __restrict__ exs4,
                                                   const float* __restrict__ exs,
                                                   const float* __restrict__ inva,
                                                   const int* __restrict__ offsets,
                                                   const int2* __restrict__ esd,
                                                   const float* __restrict__ bias,
                                                   float* __restrict__ xout,
                                                   unsigned short* __restrict__ xout_bf,
                                                   int N) {
  __shared__ float4 s_al[MAXS];
  __shared__ int s_src[MAXS];
  int c = blockIdx.x & 7;
  int nb = (blockIdx.x >> 3) * 4;
  int base = offsets[nb];
  int nend = (nb + 4 < N) ? nb + 4 : N;
  int total = offsets[nend] - base;
  int cap = total < MAXS ? total : MAXS;
  for (int idx = threadIdx.x; idx < cap; idx += 256) {
    s_al[idx] = exs4[base + idx];
    s_src[idx] = esd[base + idx].x;
  }
  __syncthreads();
  int n = nb + (threadIdx.x >> 6);
  if (n >= N) return;
  int lane = threadIdx.x & 63;
  int g = lane >> 4;   // edge subgroup within wave
  int q = lane & 15;   // 16B segment of the 256B slice row
  int hq = q >> 2;     // head of this segment
  const unsigned short* sl = hsl + (size_t)c * N * 128;
  const float* alf = (const float*)s_al;
  float acc[8] = {};
  int k0 = offsets[n], k1 = offsets[n + 1];
  int r = k0 - base + g;
  int rend = k1 - base;
  for (; r + 4 < rend; r += 8) {
    int sA, sB;
    float aA, aB;
    if (r + 4 < MAXS) {
      sA = s_src[r];
      sB = s_src[r + 4];
      aA = alf[r * 4 + hq];
      aB = alf[(r + 4) * 4 + hq];
    } else {
      sA = esd[base + r].x;
      sB = esd[base + r + 4].x;
      aA = exs[(size_t)(base + r) * 4 + hq];
      aB = exs[(size_t)(base + r + 4) * 4 + hq];
    }
    bf16x8 vA = *(const bf16x8*)&sl[((size_t)sA << 7) + q * 8];
    bf16x8 vB = *(const bf16x8*)&sl[((size_t)sB << 7) + q * 8];
#pragma unroll
    for (int j = 0; j < 8; j++)
      acc[j] += aA * bf2f((unsigned short)vA[j]) + aB * bf2f((unsigned short)vB[j]);
  }
  if (r < rend) {
    int sA;
    float aA;
    if (r < MAXS) {
      sA = s_src[r];
      aA = alf[r * 4 + hq];
    } else {
      sA = esd[base + r].x;
      aA = exs[(size_t)(base + r) * 4 + hq];
    }
    bf16x8 vA = *(const bf16x8*)&sl[((size_t)sA << 7) + q * 8];
#pragma unroll
    for (int j = 0; j < 8; j++) acc[j] += aA * bf2f((unsigned short)vA[j]);
  }
  float ia = inva[n * 4 + hq];  // 0.25/denom (head-mean folded)
#pragma unroll
  for (int j = 0; j < 8; j++) {
    float v = acc[j] * ia;
    v += __shfl_xor(v, 16);  // edge groups
    v += __shfl_xor(v, 32);
    v += __shfl_xor(v, 4);   // heads
    v += __shfl_xor(v, 8);
    acc[j] = v;
  }
  if (lane < 4) {  // lane in 0..3 holds within-head channels lane*8..+7, head-summed
    int oc = c * 32 + lane * 8;
    if (xout) {
      float4 o0 = make_float4(acc[0] + bias[oc + 0], acc[1] + bias[oc + 1],
                              acc[2] + bias[oc + 2], acc[3] + bias[oc + 3]);
      float4 o1 = make_float4(acc[4] + bias[oc + 4], acc[5] + bias[oc + 5],
                              acc[6] + bias[oc + 6], acc[7] + bias[oc + 7]);
      *(float4*)&xout[(size_t)n * CH + oc] = o0;
      *(float4*)&xout[(size_t)n * CH + oc + 4] = o1;
    }
    if (xout_bf) {
      ushort4 o0 = make_ushort4(f2bf(acc[0] + bias[oc + 0]), f2bf(acc[1] + bias[oc + 1]),
                                f2bf(acc[2] + bias[oc + 2]), f2bf(acc[3] + bias[oc + 3]));
      ushort4 o1 = make_ushort4(f2bf(acc[4] + bias[oc + 4]), f2bf(acc[5] + bias[oc + 5]),
                                f2bf(acc[6] + bias[oc + 6]), f2bf(acc[7] + bias[oc + 7]));
      *(ushort4*)&xout_bf[(size_t)n * CH + oc] = o0;
      *(ushort4*)&xout_bf[(size_t)n * CH + oc + 4] = o1;
    }
  }
}

extern "C" void kernel_launch(void* const* d_in, const int* in_sizes, int n_in,
                              void* d_out, int out_size, void* d_ws, size_t ws_size,
                              hipStream_t stream) {
  const float* x = (const float*)d_in[0];
  const int* ei = (const int*)d_in[1];
  const float* W[3] = {(const float*)d_in[2], (const float*)d_in[6], (const float*)d_in[10]};
  const float* AS[3] = {(const float*)d_in[3], (const float*)d_in[7], (const float*)d_in[11]};
  const float* AD[3] = {(const float*)d_in[4], (const float*)d_in[8], (const float*)d_in[12]};
  const float* BI[3] = {(const float*)d_in[5], (const float*)d_in[9], (const float*)d_in[13]};
  const int N = in_sizes[0] / 512;
  const int E = in_sizes[1] / 2;
  const int ET = E + N;
  const int Kd[3] = {512, 256, 256};

  char* p = (char*)d_ws;
  auto alloc = [&](size_t bytes) {
    char* r = p;
    p += (bytes + 255) & ~(size_t)255;
    return (void*)r;
  };
  unsigned short* hsl = (unsigned short*)alloc((size_t)NSLICE * N * 128 * 2);
  unsigned short* axb = (unsigned short*)alloc((size_t)N * 512 * 2);
  unsigned short* actbf = (unsigned short*)alloc((size_t)N * CH * 2);
  unsigned short* Wt[3];
  for (int i = 0; i < 3; i++) Wt[i] = (unsigned short*)alloc((size_t)HC * Kd[i] * 2);
  float* es = (float*)alloc((size_t)N * HEADS * 4);
  float* ed = (float*)alloc((size_t)N * HEADS * 4);
  float* exs = (float*)alloc((size_t)ET * HEADS * 4);
  float* inva = (float*)alloc((size_t)N * HEADS * 4);
  int* offsets = (int*)alloc((size_t)(N + 1) * 4);
  int* cursor = (int*)alloc((size_t)N * 4);
  int2* esd = (int2*)alloc((size_t)ET * 8);

  // ---- CSR build (shared by all 3 layers) ----
  hipMemsetAsync(cursor, 0, (size_t)N * 4, stream);
  k_count<<<cdiv(ET, 256), 256, 0, stream>>>(ei, E, ET, cursor);
  k_scan<<<1, 1024, 0, stream>>>(cursor, offsets, N);
  hipMemsetAsync(cursor, 0, (size_t)N * 4, stream);
  k_fill<<<cdiv(ET, 256), 256, 0, stream>>>(ei, E, ET, offsets, cursor, esd);

  // ---- weight transpose+cast, input cast ----
  for (int i = 0; i < 3; i++)
    k_transpose_w<<<dim3(Kd[i] / 32, HC / 32), 256, 0, stream>>>(W[i], Wt[i], Kd[i]);
  k_cast_bf16<<<cdiv(N * 512, 8 * 256), 256, 0, stream>>>(x, axb, N * 512);

  const unsigned short* ain = axb;
  int aggGrid = cdiv(N, 4) * 8;  // 4 waves/block x 1 node/wave, x8 slices
  for (int layer = 0; layer < 3; ++layer) {
    int K = Kd[layer];
    k_gemm_mfma<<<dim3(cdiv(N, 128), HC / 128), 256, 0, stream>>>(ain, Wt[layer], hsl, N, K);
    k_logits<<<N, 256, 0, stream>>>(hsl, AS[layer], AD[layer], es, ed, N);
    k_edge_exp<<<cdiv(ET, 256), 256, 0, stream>>>(esd, ET, (const float4*)es,
                                                  (const float4*)ed, (float4*)exs);
    k_denom<<<cdiv(N, 4), 256, 0, stream>>>(exs, offsets, inva, N);
    if (layer < 2) {
      k_aggregate<<<aggGrid, 256, 0, stream>>>(hsl, (const float4*)exs, exs, inva, offsets,
                                               esd, BI[layer], (float*)nullptr, actbf, N);
    } else {
      k_aggregate<<<aggGrid, 256, 0, stream>>>(hsl, (const float4*)exs, exs, inva, offsets,
                                               esd, BI[layer], (float*)d_out,
                                               (unsigned short*)nullptr, N);
    }
    ain = actbf;
  }
}

// Round 13
// 289.227 us; speedup vs baseline: 1.5587x; 1.0032x over previous
//
#include <hip/hip_runtime.h>
#include <hip/hip_fp16.h>
#include <math.h>

#define HEADS 4
#define CH 256
#define HC 1024
#define NSLICE 8
#define NEG_SLOPE 0.2f
#define EPSQ 1e-16f
#define MAXS 320   // staged CSR slots per block (4 nodes)
#define ASCALE (1.0f / 1024.0f)  // alpha scale: keeps exp() in fp16 range; exact pow2

typedef _Float16 f16x8 __attribute__((ext_vector_type(8)));
typedef _Float16 f16x4 __attribute__((ext_vector_type(4)));
typedef __attribute__((ext_vector_type(4))) float f32x4;

static inline int cdiv(int a, int b) { return (a + b - 1) / b; }

__device__ __forceinline__ __half2 u2h2(unsigned u) {
  union {
    unsigned u;
    __half2 h;
  } x;
  x.u = u;
  return x.h;
}
__device__ __forceinline__ void gload_lds16(const void* g, void* l) {
  __builtin_amdgcn_global_load_lds((const __attribute__((address_space(1))) void*)g,
                                   (__attribute__((address_space(3))) void*)l, 16, 0, 0);
}

// ---------------- CSR build ----------------
__global__ void k_count(const int* __restrict__ ei, int E, int ET, int* __restrict__ cnt) {
  int e = blockIdx.x * blockDim.x + threadIdx.x;
  if (e >= ET) return;
  int d = (e < E) ? ei[E + e] : (e - E);
  atomicAdd(&cnt[d], 1);
}

__global__ __launch_bounds__(1024) void k_scan(const int* __restrict__ counts,
                                               int* __restrict__ offsets, int n) {
  __shared__ int wsum[16];
  __shared__ int carry_s;
  int lane = threadIdx.x & 63, wv = threadIdx.x >> 6;
  if (threadIdx.x == 0) carry_s = 0;
  __syncthreads();
  for (int base = 0; base < n; base += 1024) {
    int i = base + threadIdx.x;
    int orig = (i < n) ? counts[i] : 0;
    int v = orig;
#pragma unroll
    for (int off = 1; off < 64; off <<= 1) {
      int t = __shfl_up(v, off);
      if (lane >= off) v += t;
    }
    if (lane == 63) wsum[wv] = v;
    __syncthreads();
    int carry = carry_s;
    int wpre = 0;
#pragma unroll
    for (int w = 0; w < 16; w++) wpre += (w < wv) ? wsum[w] : 0;
    int incl = v + wpre;
    if (i < n) offsets[i] = carry + incl - orig;
    __syncthreads();
    if (threadIdx.x == 1023) carry_s = carry + incl;
    __syncthreads();
  }
  if (threadIdx.x == 0) offsets[n] = carry_s;
}

__global__ void k_fill(const int* __restrict__ ei, int E, int ET,
                       const int* __restrict__ offsets, int* __restrict__ cursor,
                       int2* __restrict__ esd) {
  int e = blockIdx.x * blockDim.x + threadIdx.x;
  if (e >= ET) return;
  int s = (e < E) ? ei[e] : (e - E);
  int d = (e < E) ? ei[E + e] : (e - E);
  int pos = offsets[d] + atomicAdd(&cursor[d], 1);
  esd[pos] = make_int2(s, d);
}

// ---------------- W transpose + cast to fp16 ----------------
__global__ __launch_bounds__(256) void k_transpose_w(const float* __restrict__ W,
                                                     _Float16* __restrict__ Wt, int K) {
  __shared__ float tile[32][33];
  int tx = threadIdx.x & 31, ty = threadIdx.x >> 5;
  int k0 = blockIdx.x * 32, n0 = blockIdx.y * 32;
#pragma unroll
  for (int r = ty; r < 32; r += 8) tile[r][tx] = W[(size_t)(k0 + r) * HC + n0 + tx];
  __syncthreads();
#pragma unroll
  for (int r = ty; r < 32; r += 8)
    Wt[(size_t)(n0 + r) * K + k0 + tx] = (_Float16)tile[tx][r];
}

// ---------------- cast fp32 -> fp16 ----------------
__global__ void k_cast_f16(const float* __restrict__ in, _Float16* __restrict__ out, int n) {
  int i = (blockIdx.x * blockDim.x + threadIdx.x) * 8;
  if (i >= n) return;
  float4 a = *(const float4*)&in[i];
  float4 b = *(const float4*)&in[i + 4];
  f16x8 o;
  o[0] = (_Float16)a.x;
  o[1] = (_Float16)a.y;
  o[2] = (_Float16)a.z;
  o[3] = (_Float16)a.w;
  o[4] = (_Float16)b.x;
  o[5] = (_Float16)b.y;
  o[6] = (_Float16)b.z;
  o[7] = (_Float16)b.w;
  *(f16x8*)&out[i] = o;
}

// ---------------- fp16 MFMA GEMM, epilogue writes slice-major hsl[c][n][128] ----
__global__ __launch_bounds__(256) void k_gemm_mfma(const _Float16* __restrict__ A,
                                                   const _Float16* __restrict__ Bt,
                                                   _Float16* __restrict__ hsl, int M, int K) {
  __shared__ _Float16 sA[2][128 * 32];
  __shared__ _Float16 sB[2][128 * 32];
  int t = threadIdx.x;
  int lane = t & 63, wv = t >> 6;
  int wr = wv >> 1, wc = wv & 1;
  int row0 = blockIdx.x * 128, col0 = blockIdx.y * 128;
  int l15 = lane & 15, l4 = lane >> 4;

  f32x4 acc[4][4] = {};

  auto stage = [&](_Float16* sdst, const _Float16* g, int grow0, int rowmax, int k0) {
#pragma unroll
    for (int q = 0; q < 2; ++q) {
      int r = grow0 + q * 64 + (t >> 2);
      if (r > rowmax) r = rowmax;
      const _Float16* gp = g + (size_t)r * K + k0 + (t & 3) * 8;
      gload_lds16(gp, sdst + q * 2048 + t * 8);
    }
  };

  int KT = K / 32;
  stage(sA[0], A, row0, M - 1, 0);
  stage(sB[0], Bt, col0, HC - 1, 0);
  int cur = 0;
  for (int kt = 0; kt < KT; ++kt) {
    __syncthreads();
    if (kt + 1 < KT) {
      stage(sA[cur ^ 1], A, row0, M - 1, (kt + 1) * 32);
      stage(sB[cur ^ 1], Bt, col0, HC - 1, (kt + 1) * 32);
    }
    f16x8 af[4], bfr[4];
#pragma unroll
    for (int i = 0; i < 4; i++)
      af[i] = *(f16x8*)&sA[cur][(wr * 64 + i * 16 + l15) * 32 + l4 * 8];
#pragma unroll
    for (int j = 0; j < 4; j++)
      bfr[j] = *(f16x8*)&sB[cur][(wc * 64 + j * 16 + l15) * 32 + l4 * 8];
#pragma unroll
    for (int i = 0; i < 4; i++)
#pragma unroll
      for (int j = 0; j < 4; j++)
        acc[i][j] = __builtin_amdgcn_mfma_f32_16x16x32_f16(af[i], bfr[j], acc[i][j], 0, 0, 0);
    cur ^= 1;
  }
#pragma unroll
  for (int i = 0; i < 4; i++) {
#pragma unroll
    for (int j = 0; j < 4; j++) {
      int col = col0 + wc * 64 + j * 16 + l15;
      int head = col >> 8;
      int c = (col >> 5) & 7;
      int jj = col & 31;
      size_t sbase = ((size_t)c * M) * 128 + (head << 5) + jj;
#pragma unroll
      for (int r = 0; r < 4; r++) {
        int row = row0 + wr * 64 + i * 16 + l4 * 4 + r;
        if (row < M) hsl[sbase + (size_t)row * 128] = (_Float16)acc[i][j][r];
      }
    }
  }
}

// ---------------- per-node logits from slice-major hsl (fp16) ----------------
__global__ __launch_bounds__(256) void k_logits(const _Float16* __restrict__ hsl,
                                                const float* __restrict__ as_,
                                                const float* __restrict__ ad_,
                                                float* __restrict__ es, float* __restrict__ ed,
                                                int M) {
  __shared__ float lds_s[4][64];
  __shared__ float lds_d[4][64];
  int n = blockIdx.x;
  int t = threadIdx.x;
  int c = t >> 5, chunk = t & 31;
  int head = chunk >> 3, q = chunk * 4;
  f16x4 hv = *(const f16x4*)&hsl[((size_t)c * M + n) * 128 + q];
  int ch = head * 256 + c * 32 + (q & 31);
  float4 s4 = *(const float4*)&as_[ch];
  float4 d4 = *(const float4*)&ad_[ch];
  float h0 = (float)hv[0], h1 = (float)hv[1], h2 = (float)hv[2], h3 = (float)hv[3];
  float ds = h0 * s4.x + h1 * s4.y + h2 * s4.z + h3 * s4.w;
  float dd = h0 * d4.x + h1 * d4.y + h2 * d4.z + h3 * d4.w;
  int g = c * 8 + (chunk & 7);
  lds_s[head][g] = ds;
  lds_d[head][g] = dd;
  __syncthreads();
  int wv = t >> 6, l = t & 63;
  float vs = lds_s[wv][l];
  float vd = lds_d[wv][l];
#pragma unroll
  for (int off = 32; off; off >>= 1) {
    vs += __shfl_xor(vs, off);
    vd += __shfl_xor(vd, off);
  }
  if (l == 0) {
    es[n * HEADS + wv] = vs;
    ed[n * HEADS + wv] = vd;
  }
}

// ---------------- slot-ordered edge exp: fp32 exs (denom) + packed-dup fp16 alpha ----
__global__ void k_edge_exp(const int2* __restrict__ esd, int ET,
                           const float4* __restrict__ es4, const float4* __restrict__ ed4,
                           float4* __restrict__ exs4, __half2* __restrict__ exsp) {
  int k = blockIdx.x * blockDim.x + threadIdx.x;
  if (k >= ET) return;
  int2 sd = esd[k];
  float4 a = es4[sd.x], b = ed4[sd.y];
  float v0 = a.x + b.x, v1 = a.y + b.y, v2 = a.z + b.z, v3 = a.w + b.w;
  v0 = v0 > 0.f ? v0 : NEG_SLOPE * v0;
  v1 = v1 > 0.f ? v1 : NEG_SLOPE * v1;
  v2 = v2 > 0.f ? v2 : NEG_SLOPE * v2;
  v3 = v3 > 0.f ? v3 : NEG_SLOPE * v3;
  float e0 = __expf(v0), e1 = __expf(v1), e2 = __expf(v2), e3 = __expf(v3);
  exs4[k] = make_float4(e0, e1, e2, e3);
  size_t kb = (size_t)k * 4;
  exsp[kb + 0] = __float2half2_rn(e0 * ASCALE);
  exsp[kb + 1] = __float2half2_rn(e1 * ASCALE);
  exsp[kb + 2] = __float2half2_rn(e2 * ASCALE);
  exsp[kb + 3] = __float2half2_rn(e3 * ASCALE);
}

// ---------------- per-node inverse denom (folds head-mean and 1/ASCALE) ----------------
__global__ __launch_bounds__(256) void k_denom(const float* __restrict__ exs,
                                               const int* __restrict__ offsets,
                                               float* __restrict__ inva, int N) {
  int lane = threadIdx.x & 63;
  int n = blockIdx.x * 4 + (threadIdx.x >> 6);
  if (n >= N) return;
  int sub = lane >> 2, h = lane & 3;
  int k0 = offsets[n], k1 = offsets[n + 1];
  float sum = 0.f;
  for (int k = k0 + sub; k < k1; k += 16) sum += exs[k * 4 + h];
#pragma unroll
  for (int off = 4; off < 64; off <<= 1) sum += __shfl_xor(sum, off);
  if (lane < 4) inva[n * 4 + h] = (0.25f / ASCALE) / (sum + EPSQ);
}

// ---------------- XCD-sliced aggregation: packed v_pk_fma_f16 inner loop ----------------
// Block = 4 waves = 4 consecutive nodes of slice c (blockIdx&7 -> XCD). Stage
// {packed alpha[4], src} per CSR slot into LDS, barrier. Inner loop per edge:
// 2 conflict-free ds_read_b32 + 1 dwordx4 h-burst + 4 __hfma2 (v_pk_fma_f16)
// -- no unpack. fp16 accumulators hold only deg/4 ~ 4-5 terms (alpha <= 32
// after 2^-10 scale), fp32 conversion once in epilogue; 2^10 folded into inva.
__global__ __launch_bounds__(256) void k_aggregate(const _Float16* __restrict__ hsl,
                                                   const uint4* __restrict__ exsp4,
                                                   const __half2* __restrict__ exsp,
                                                   const float* __restrict__ inva,
                                                   const int* __restrict__ offsets,
                                                   const int2* __restrict__ esd,
                                                   const float* __restrict__ bias,
                                                   float* __restrict__ xout,
                                                   _Float16* __restrict__ xout_h, int N) {
  __shared__ uint4 s_ap[MAXS];
  __shared__ int s_src[MAXS];
  int c = blockIdx.x & 7;
  int nb = (blockIdx.x >> 3) * 4;
  int base = offsets[nb];
  int nend = (nb + 4 < N) ? nb + 4 : N;
  int total = offsets[nend] - base;
  int cap = total < MAXS ? total : MAXS;
  for (int idx = threadIdx.x; idx < cap; idx += 256) {
    s_ap[idx] = exsp4[base + idx];
    s_src[idx] = esd[base + idx].x;
  }
  __syncthreads();
  int n = nb + (threadIdx.x >> 6);
  if (n >= N) return;
  int lane = threadIdx.x & 63;
  int g = lane >> 4;
  int q = lane & 15;
  int hq = q >> 2;
  const _Float16* sl = hsl + (size_t)c * N * 128;
  const __half2* aph = (const __half2*)s_ap;
  __half2 z2 = __float2half2_rn(0.f);
  __half2 acc2[4] = {z2, z2, z2, z2};
  int k0 = offsets[n], k1 = offsets[n + 1];
  int r = k0 - base + g;
  int rend = k1 - base;
  for (; r + 4 < rend; r += 8) {
    int sA, sB;
    __half2 aA, aB;
    if (r + 4 < MAXS) {
      sA = s_src[r];
      sB = s_src[r + 4];
      aA = aph[r * 4 + hq];
      aB = aph[(r + 4) * 4 + hq];
    } else {
      sA = esd[base + r].x;
      sB = esd[base + r + 4].x;
      aA = exsp[(size_t)(base + r) * 4 + hq];
      aB = exsp[(size_t)(base + r + 4) * 4 + hq];
    }
    uint4 hA = *(const uint4*)&sl[((size_t)sA << 7) + q * 8];
    uint4 hB = *(const uint4*)&sl[((size_t)sB << 7) + q * 8];
    acc2[0] = __hfma2(aA, u2h2(hA.x), acc2[0]);
    acc2[1] = __hfma2(aA, u2h2(hA.y), acc2[1]);
    acc2[2] = __hfma2(aA, u2h2(hA.z), acc2[2]);
    acc2[3] = __hfma2(aA, u2h2(hA.w), acc2[3]);
    acc2[0] = __hfma2(aB, u2h2(hB.x), acc2[0]);
    acc2[1] = __hfma2(aB, u2h2(hB.y), acc2[1]);
    acc2[2] = __hfma2(aB, u2h2(hB.z), acc2[2]);
    acc2[3] = __hfma2(aB, u2h2(hB.w), acc2[3]);
  }
  if (r < rend) {
    int sA;
    __half2 aA;
    if (r < MAXS) {
      sA = s_src[r];
      aA = aph[r * 4 + hq];
    } else {
      sA = esd[base + r].x;
      aA = exsp[(size_t)(base + r) * 4 + hq];
    }
    uint4 hA = *(const uint4*)&sl[((size_t)sA << 7) + q * 8];
    acc2[0] = __hfma2(aA, u2h2(hA.x), acc2[0]);
    acc2[1] = __hfma2(aA, u2h2(hA.y), acc2[1]);
    acc2[2] = __hfma2(aA, u2h2(hA.z), acc2[2]);
    acc2[3] = __hfma2(aA, u2h2(hA.w), acc2[3]);
  }
  float ia = inva[n * 4 + hq];  // (0.25/ASCALE)/denom
  float acc[8];
#pragma unroll
  for (int j = 0; j < 4; j++) {
    acc[2 * j] = __low2float(acc2[j]);
    acc[2 * j + 1] = __high2float(acc2[j]);
  }
#pragma unroll
  for (int j = 0; j < 8; j++) {
    float v = acc[j] * ia;
    v += __shfl_xor(v, 16);  // edge groups
    v += __shfl_xor(v, 32);
    v += __shfl_xor(v, 4);   // heads
    v += __shfl_xor(v, 8);
    acc[j] = v;
  }
  if (lane < 4) {
    int oc = c * 32 + lane * 8;
    if (xout) {
      float4 o0 = make_float4(acc[0] + bias[oc + 0], acc[1] + bias[oc + 1],
                              acc[2] + bias[oc + 2], acc[3] + bias[oc + 3]);
      float4 o1 = make_float4(acc[4] + bias[oc + 4], acc[5] + bias[oc + 5],
                              acc[6] + bias[oc + 6], acc[7] + bias[oc + 7]);
      *(float4*)&xout[(size_t)n * CH + oc] = o0;
      *(float4*)&xout[(size_t)n * CH + oc + 4] = o1;
    }
    if (xout_h) {
      f16x8 o;
#pragma unroll
      for (int j = 0; j < 8; j++) o[j] = (_Float16)(acc[j] + bias[oc + j]);
      *(f16x8*)&xout_h[(size_t)n * CH + oc] = o;
    }
  }
}

extern "C" void kernel_launch(void* const* d_in, const int* in_sizes, int n_in,
                              void* d_out, int out_size, void* d_ws, size_t ws_size,
                              hipStream_t stream) {
  const float* x = (const float*)d_in[0];
  const int* ei = (const int*)d_in[1];
  const float* W[3] = {(const float*)d_in[2], (const float*)d_in[6], (const float*)d_in[10]};
  const float* AS[3] = {(const float*)d_in[3], (const float*)d_in[7], (const float*)d_in[11]};
  const float* AD[3] = {(const float*)d_in[4], (const float*)d_in[8], (const float*)d_in[12]};
  const float* BI[3] = {(const float*)d_in[5], (const float*)d_in[9], (const float*)d_in[13]};
  const int N = in_sizes[0] / 512;
  const int E = in_sizes[1] / 2;
  const int ET = E + N;
  const int Kd[3] = {512, 256, 256};

  char* p = (char*)d_ws;
  auto alloc = [&](size_t bytes) {
    char* r = p;
    p += (bytes + 255) & ~(size_t)255;
    return (void*)r;
  };
  _Float16* hsl = (_Float16*)alloc((size_t)NSLICE * N * 128 * 2);
  _Float16* axh = (_Float16*)alloc((size_t)N * 512 * 2);
  _Float16* acth = (_Float16*)alloc((size_t)N * CH * 2);
  _Float16* Wt[3];
  for (int i = 0; i < 3; i++) Wt[i] = (_Float16*)alloc((size_t)HC * Kd[i] * 2);
  float* es = (float*)alloc((size_t)N * HEADS * 4);
  float* ed = (float*)alloc((size_t)N * HEADS * 4);
  float* exs = (float*)alloc((size_t)ET * HEADS * 4);
  __half2* exsp = (__half2*)alloc((size_t)ET * HEADS * 4);
  float* inva = (float*)alloc((size_t)N * HEADS * 4);
  int* offsets = (int*)alloc((size_t)(N + 1) * 4);
  int* cursor = (int*)alloc((size_t)N * 4);
  int2* esd = (int2*)alloc((size_t)ET * 8);

  // ---- CSR build (shared by all 3 layers) ----
  hipMemsetAsync(cursor, 0, (size_t)N * 4, stream);
  k_count<<<cdiv(ET, 256), 256, 0, stream>>>(ei, E, ET, cursor);
  k_scan<<<1, 1024, 0, stream>>>(cursor, offsets, N);
  hipMemsetAsync(cursor, 0, (size_t)N * 4, stream);
  k_fill<<<cdiv(ET, 256), 256, 0, stream>>>(ei, E, ET, offsets, cursor, esd);

  // ---- weight transpose+cast, input cast ----
  for (int i = 0; i < 3; i++)
    k_transpose_w<<<dim3(Kd[i] / 32, HC / 32), 256, 0, stream>>>(W[i], Wt[i], Kd[i]);
  k_cast_f16<<<cdiv(N * 512, 8 * 256), 256, 0, stream>>>(x, axh, N * 512);

  const _Float16* ain = axh;
  int aggGrid = cdiv(N, 4) * 8;
  for (int layer = 0; layer < 3; ++layer) {
    int K = Kd[layer];
    k_gemm_mfma<<<dim3(cdiv(N, 128), HC / 128), 256, 0, stream>>>(ain, Wt[layer], hsl, N, K);
    k_logits<<<N, 256, 0, stream>>>(hsl, AS[layer], AD[layer], es, ed, N);
    k_edge_exp<<<cdiv(ET, 256), 256, 0, stream>>>(esd, ET, (const float4*)es,
                                                  (const float4*)ed, (float4*)exs, exsp);
    k_denom<<<cdiv(N, 4), 256, 0, stream>>>(exs, offsets, inva, N);
    if (layer < 2) {
      k_aggregate<<<aggGrid, 256, 0, stream>>>(hsl, (const uint4*)exsp, exsp, inva, offsets,
                                               esd, BI[layer], (float*)nullptr, acth, N);
    } else {
      k_aggregate<<<aggGrid, 256, 0, stream>>>(hsl, (const uint4*)exsp, exsp, inva, offsets,
                                               esd, BI[layer], (float*)d_out,
                                               (_Float16*)nullptr, N);
    }
    ain = acth;
  }
}